// Round 7
// baseline (113.680 us; speedup 1.0000x reference)
//
#include <hip/hip_runtime.h>
#include <cstdint>

#define LL 1024
#define DD 1024
#define NB 16
#define NHH 8

typedef __bf16 bf16x8 __attribute__((ext_vector_type(8)));
typedef float f32x4 __attribute__((ext_vector_type(4)));
typedef unsigned short u16;

#define GPTR(x) ((const __attribute__((address_space(1))) void*)(x))
#define LPTR(x) ((__attribute__((address_space(3))) void*)(x))
#define BAR()   __builtin_amdgcn_s_barrier()
#define LGKM0() asm volatile("s_waitcnt lgkmcnt(0)" ::: "memory")
#define VMC(N)  asm volatile("s_waitcnt vmcnt(" #N ")" ::: "memory")

static __device__ __forceinline__ u16 f2b(float f) {
  unsigned int u = __float_as_uint(f);
  u += 0x7FFFu + ((u >> 16) & 1u);
  return (u16)(u >> 16);
}

// ---------------------------------------------------------------------------
// Fused prologue: one dispatch, grid-sectioned.
//   blocks [0,1024)      : weff rows  (w_eff = head-sum of out_w, bf16 + S)
//   blocks [1024,2048)   : softmax rows of tril(conv_w) (faithful exp(0) terms)
//   blocks [2048,4096)   : x f32 -> bf16 streaming convert (grid-stride)
// ---------------------------------------------------------------------------
__global__ __launch_bounds__(256) void prep_kernel(const float* __restrict__ x,
                                                   const float* __restrict__ conv_w,
                                                   const float* __restrict__ out_w,
                                                   u16* __restrict__ xb,
                                                   u16* __restrict__ Wb,
                                                   u16* __restrict__ weff,
                                                   float* __restrict__ S) {
  const int blk = blockIdx.x;
  const int t = threadIdx.x;
  __shared__ float red[256];

  if (blk < 1024) {
    const int o = blk;
    const float4* row = (const float4*)(out_w + (size_t)o * (DD * NHH));
    float4 s4 = {0.f, 0.f, 0.f, 0.f};
#pragma unroll
    for (int h = 0; h < NHH; ++h) {
      float4 v = row[h * 256 + t];
      s4.x += v.x; s4.y += v.y; s4.z += v.z; s4.w += v.w;
    }
    ushort4 p;
    p.x = f2b(s4.x); p.y = f2b(s4.y); p.z = f2b(s4.z); p.w = f2b(s4.w);
    *(ushort4*)&weff[(size_t)o * DD + t * 4] = p;
    red[t] = s4.x + s4.y + s4.z + s4.w;
    __syncthreads();
    for (int st = 128; st > 0; st >>= 1) {
      if (t < st) red[t] += red[t + st];
      __syncthreads();
    }
    if (t == 0) S[o] = red[0];
  } else if (blk < 2048) {
    const int f = blk - 1024;
    float z[4];
    float mx = -1e30f;
#pragma unroll
    for (int i = 0; i < 4; ++i) {
      int d = t + i * 256;
      float v = conv_w[(size_t)f * LL + d];
      z[i] = (d <= f) ? v : 0.f;
      mx = fmaxf(mx, z[i]);
    }
    red[t] = mx;
    __syncthreads();
    for (int st = 128; st > 0; st >>= 1) {
      if (t < st) red[t] = fmaxf(red[t], red[t + st]);
      __syncthreads();
    }
    mx = red[0];
    __syncthreads();
    float e[4], s = 0.f;
#pragma unroll
    for (int i = 0; i < 4; ++i) { e[i] = expf(z[i] - mx); s += e[i]; }
    red[t] = s;
    __syncthreads();
    for (int st = 128; st > 0; st >>= 1) {
      if (t < st) red[t] += red[t + st];
      __syncthreads();
    }
    float inv = 1.f / red[0];
#pragma unroll
    for (int i = 0; i < 4; ++i) Wb[(size_t)f * LL + t + i * 256] = f2b(e[i] * inv);
  } else {
    const int n8 = (NB * LL * DD) / 8;
    int i = (blk - 2048) * 256 + t;
    const int stride = 2048 * 256;
    for (; i < n8; i += stride) {
      float4 v0 = ((const float4*)x)[2 * i];
      float4 v1 = ((const float4*)x)[2 * i + 1];
      uint4 p;
      p.x = (unsigned)f2b(v0.x) | ((unsigned)f2b(v0.y) << 16);
      p.y = (unsigned)f2b(v0.z) | ((unsigned)f2b(v0.w) << 16);
      p.z = (unsigned)f2b(v1.x) | ((unsigned)f2b(v1.y) << 16);
      p.w = (unsigned)f2b(v1.z) | ((unsigned)f2b(v1.w) << 16);
      ((uint4*)xb)[i] = p;
    }
  }
}

// ---------------------------------------------------------------------------
// 16-wave 256x256 GEMM, BK=64, counted-vmcnt, same T2 swizzle as round-4.
//   16 waves in a 4x4 grid, 64x64 per wave: acc 16xf32x4 (~116 VGPR total)
//   -> 16 waves/CU (4/SIMD), double the round-6 occupancy.
// Per K-tile: 2 ks-phases {8 ds_read, BAR, LGKM0, MFMA, BAR}; staging of
// tile t+2 issued after all reads of buf[cur] are barrier-proven complete;
// VMC(4) at tile end keeps next tile's 4 loads in flight (2-deep pipeline).
// EPI=0: C bf16 (Zt). EPI=1: C f32 + conv_b[r]*S[c] + out_b[c].
// ---------------------------------------------------------------------------
__device__ __forceinline__ void stageTile16(const u16* __restrict__ g, u16* l,
                                            int wave, int lane) {
  const int rlo = lane >> 3;
  const int sl = (lane & 7) ^ rlo;       // pre-swizzled source slot
#pragma unroll
  for (int j = 0; j < 2; ++j) {
    const u16* src = g + (size_t)(j * 128 + wave * 8 + rlo) * 1024 + sl * 8;
    __builtin_amdgcn_global_load_lds(GPTR(src), LPTR(l + j * 8192 + wave * 512), 16, 0, 0);
  }
}

__device__ __forceinline__ bf16x8 ldsRead(const u16* l, int row, int slot) {
  int off = row * 64 + (((slot) ^ (row & 7)) << 3);
  return __builtin_bit_cast(bf16x8, *(const uint4*)(l + off));
}

template <int EPI>
__global__ __launch_bounds__(1024, 4) void gemm16(const u16* __restrict__ A,
                                                  const u16* __restrict__ Bm,
                                                  void* __restrict__ Cout,
                                                  const float* __restrict__ conv_b,
                                                  const float* __restrict__ S,
                                                  const float* __restrict__ out_b) {
  extern __shared__ u16 lds[];
  u16* A0 = lds;
  u16* B0 = lds + 16384;
  u16* A1 = lds + 32768;
  u16* B1 = lds + 49152;

  int bid = blockIdx.x;
  bid = (bid & 7) * 32 + (bid >> 3);          // T1: contiguous chunk per XCD
  const int b = bid >> 4;
  const int tm = (bid >> 2) & 3;
  const int tn = bid & 3;

  const int tid = threadIdx.x, lane = tid & 63, wave = tid >> 6;  // 0..15
  const int wm = wave >> 2, wn = wave & 3;    // 4 x 4 waves
  const int lrow = lane & 15, kg = lane >> 4;

  const u16* Ablk = A + (size_t)(tm * 256) * 1024;
  const u16* Bblk = Bm + (size_t)b * (1024 * 1024) + (size_t)(tn * 256) * 1024;

  f32x4 acc[4][4];
#pragma unroll
  for (int i = 0; i < 4; ++i)
#pragma unroll
    for (int j = 0; j < 4; ++j) acc[i][j] = (f32x4){0.f, 0.f, 0.f, 0.f};

  bf16x8 af[4], bf[4];

  auto readA = [&](const u16* Ab, int ks) {
#pragma unroll
    for (int q = 0; q < 4; ++q)
      af[q] = ldsRead(Ab, wm * 64 + q * 16 + lrow, kg + 4 * ks);
  };
  auto readB = [&](const u16* Bb, int ks) {
#pragma unroll
    for (int n = 0; n < 4; ++n)
      bf[n] = ldsRead(Bb, wn * 64 + n * 16 + lrow, kg + 4 * ks);
  };
  auto mfmaN = [&](int n0, int nn) {
    __builtin_amdgcn_s_setprio(1);
#pragma unroll
    for (int q = 0; q < 4; ++q)
#pragma unroll
      for (int n = 0; n < 4; ++n)
        if (n >= n0 && n < n0 + nn)
          acc[q][n] = __builtin_amdgcn_mfma_f32_16x16x32_bf16(af[q], bf[n], acc[q][n], 0, 0, 0);
    __builtin_amdgcn_s_setprio(0);
  };

  // prologue: t0 -> buf0, t1 -> buf1 (4 loads each); wait t0, t1 in flight
  stageTile16(Ablk, A0, wave, lane);
  stageTile16(Bblk, B0, wave, lane);
  stageTile16(Ablk + 64, A1, wave, lane);
  stageTile16(Bblk + 64, B1, wave, lane);
  VMC(4);
  BAR();

  for (int i = 0; i < 7; ++i) {
    const int t2 = 2 * i + 2, t3 = 2 * i + 3;
    // ---- tile 2i from buf0 ----
    readA(A0, 0); readB(B0, 0); BAR(); LGKM0(); mfmaN(0, 4); BAR();
    readA(A0, 1); readB(B0, 1); BAR(); LGKM0(); mfmaN(0, 2); BAR();  // all reads of buf0 proven done
    stageTile16(Ablk + t2 * 64, A0, wave, lane);
    stageTile16(Bblk + t2 * 64, B0, wave, lane);
    mfmaN(2, 2); VMC(4); BAR();               // t(2i+1) loads complete, t2 in flight
    // ---- tile 2i+1 from buf1 ----
    readA(A1, 0); readB(B1, 0); BAR(); LGKM0(); mfmaN(0, 4); BAR();
    readA(A1, 1); readB(B1, 1); BAR(); LGKM0(); mfmaN(0, 2); BAR();
    stageTile16(Ablk + t3 * 64, A1, wave, lane);
    stageTile16(Bblk + t3 * 64, B1, wave, lane);
    mfmaN(2, 2); VMC(4); BAR();
  }
  // epilogue tiles 14 (buf0) and 15 (buf1), no staging
  readA(A0, 0); readB(B0, 0); BAR(); LGKM0(); mfmaN(0, 4); BAR();
  readA(A0, 1); readB(B0, 1); BAR(); LGKM0(); mfmaN(0, 4); VMC(0); BAR();
  readA(A1, 0); readB(B1, 0); BAR(); LGKM0(); mfmaN(0, 4); BAR();
  readA(A1, 1); readB(B1, 1); BAR(); LGKM0(); mfmaN(0, 4);

  // every wave LGKM0'd before its final MFMAs -> all K-loop ds_reads complete.
  BAR();

  if constexpr (EPI == 0) {
    // acc -> LDS (256x256 bf16 = 128 KiB, bank-swizzled), then coalesced store
    u16* E = lds;
#pragma unroll
    for (int q = 0; q < 4; ++q)
#pragma unroll
      for (int n = 0; n < 4; ++n)
#pragma unroll
        for (int j = 0; j < 4; ++j) {
          int r = wm * 64 + q * 16 + kg * 4 + j;
          int c = wn * 64 + n * 16 + lrow;
          E[r * 256 + (c ^ (((r >> 2) & 3) << 4))] = f2b(acc[q][n][j]);
        }
    __syncthreads();
    u16* Cb = (u16*)Cout + (size_t)b * (1024 * 1024) + (size_t)(tm * 256) * 1024 + tn * 256;
#pragma unroll
    for (int i = 0; i < 8; ++i) {
      int r = i * 32 + (tid >> 5);
      int cl = (tid & 31) * 8;
      uint4 v = *(const uint4*)&E[r * 256 + (cl ^ (((r >> 2) & 3) << 4))];
      *(uint4*)&Cb[(size_t)r * 1024 + cl] = v;
    }
  } else {
    // two 128-row halves through LDS (128 KiB f32 each), bias fused at write
    float* Ef = (float*)lds;
    float* Cf = (float*)Cout + (size_t)b * (1024 * 1024) + (size_t)(tm * 256) * 1024 + tn * 256;
#pragma unroll
    for (int h = 0; h < 2; ++h) {
      if (h) __syncthreads();  // half-0 readers done before overwrite
#pragma unroll
      for (int q2 = 0; q2 < 2; ++q2) {
        int q = 2 * h + q2;
#pragma unroll
        for (int n = 0; n < 4; ++n) {
          int c = wn * 64 + n * 16 + lrow;
          float sc = S[tn * 256 + c], ob = out_b[tn * 256 + c];
#pragma unroll
          for (int j = 0; j < 4; ++j) {
            int li = wm * 32 + q2 * 16 + kg * 4 + j;            // 0..127
            int rg = tm * 256 + wm * 64 + q * 16 + kg * 4 + j;  // global row
            Ef[li * 256 + (c ^ ((li & 4) << 2))] = acc[q][n][j] + conv_b[rg] * sc + ob;
          }
        }
      }
      __syncthreads();
#pragma unroll
      for (int i = 0; i < 4; ++i) {
        int li = i * 32 + (tid >> 5);
        int cl = (tid & 31) * 8;
        int cs = cl ^ ((li & 4) << 2);
        float4 v0 = *(const float4*)&Ef[li * 256 + cs];
        float4 v1 = *(const float4*)&Ef[li * 256 + cs + 4];
        int r = (li >> 5) * 64 + h * 32 + (li & 31);
        *(float4*)&Cf[(size_t)r * 1024 + cl] = v0;
        *(float4*)&Cf[(size_t)r * 1024 + cl + 4] = v1;
      }
    }
  }
}

// ---------------------------------------------------------------------------
// Fallback 128^2 2-phase kernels (used only if 128KB-LDS attr or ws fails)
// ---------------------------------------------------------------------------
__global__ __launch_bounds__(256) void gemmA_f32(const u16* __restrict__ weff,
                                                 const float* __restrict__ x,
                                                 u16* __restrict__ Zt) {
  __shared__ u16 Al[128 * 32];
  __shared__ u16 Bl[128 * 32];
  const int b = blockIdx.y;
  const int tid = threadIdx.x, lane = tid & 63, wave = tid >> 6;
  const int wm = wave >> 1, wn = wave & 1;
  const int tm = blockIdx.x >> 3, tn = blockIdx.x & 7;
  const int lrow = lane & 15, kg = lane >> 4;
  const float* xbp = x + (size_t)b * LL * DD;
  f32x4 acc[4][4];
#pragma unroll
  for (int i = 0; i < 4; ++i)
#pragma unroll
    for (int j = 0; j < 4; ++j) acc[i][j] = (f32x4){0.f, 0.f, 0.f, 0.f};
  const int brow = tid >> 2, bcol = (tid & 3) * 8;
  const int arow = lane >> 2, acol = (lane & 3) * 8;
  for (int k0 = 0; k0 < DD; k0 += 32) {
#pragma unroll
    for (int cc = 0; cc < 2; ++cc) {
      int c = 2 * wave + cc;
      const u16* g = weff + (size_t)(tm * 128 + c * 16 + arow) * DD + k0 + acol;
      __builtin_amdgcn_global_load_lds(GPTR(g), LPTR(Al + c * 512), 16, 0, 0);
    }
#pragma unroll
    for (int ch = 0; ch < 2; ++ch) {
      const float* gp = xbp + (size_t)(tn * 128 + ch * 64 + brow) * DD + k0 + bcol;
      float4 v0 = *(const float4*)gp;
      float4 v1 = *(const float4*)(gp + 4);
      uint4 p;
      p.x = (unsigned)f2b(v0.x) | ((unsigned)f2b(v0.y) << 16);
      p.y = (unsigned)f2b(v0.z) | ((unsigned)f2b(v0.w) << 16);
      p.z = (unsigned)f2b(v1.x) | ((unsigned)f2b(v1.y) << 16);
      p.w = (unsigned)f2b(v1.z) | ((unsigned)f2b(v1.w) << 16);
      *(uint4*)&Bl[(ch * 64 + brow) * 32 + bcol] = p;
    }
    __syncthreads();
    bf16x8 a2[4], b2[4];
#pragma unroll
    for (int mi = 0; mi < 4; ++mi)
      a2[mi] = __builtin_bit_cast(bf16x8, *(const uint4*)&Al[(wm * 64 + mi * 16 + lrow) * 32 + kg * 8]);
#pragma unroll
    for (int ni = 0; ni < 4; ++ni)
      b2[ni] = __builtin_bit_cast(bf16x8, *(const uint4*)&Bl[(wn * 64 + ni * 16 + lrow) * 32 + kg * 8]);
#pragma unroll
    for (int mi = 0; mi < 4; ++mi)
#pragma unroll
      for (int ni = 0; ni < 4; ++ni)
        acc[mi][ni] = __builtin_amdgcn_mfma_f32_16x16x32_bf16(a2[mi], b2[ni], acc[mi][ni], 0, 0, 0);
    __syncthreads();
  }
  u16* Zb = Zt + (size_t)b * DD * LL;
#pragma unroll
  for (int mi = 0; mi < 4; ++mi)
#pragma unroll
    for (int ni = 0; ni < 4; ++ni)
#pragma unroll
      for (int j = 0; j < 4; ++j) {
        int r = tm * 128 + wm * 64 + mi * 16 + kg * 4 + j;
        int c = tn * 128 + wn * 64 + ni * 16 + lrow;
        Zb[(size_t)r * LL + c] = f2b(acc[mi][ni][j]);
      }
}

__global__ __launch_bounds__(256) void gemmB2(const u16* __restrict__ Wm,
                                              const u16* __restrict__ Zt,
                                              const float* __restrict__ conv_b,
                                              const float* __restrict__ S,
                                              const float* __restrict__ out_b,
                                              float* __restrict__ out) {
  __shared__ u16 Al[128 * 32];
  __shared__ u16 Bl[128 * 32];
  const int b = blockIdx.y;
  const int tid = threadIdx.x, lane = tid & 63, wave = tid >> 6;
  const int wm = wave >> 1, wn = wave & 1;
  const int tm = blockIdx.x >> 3, tn = blockIdx.x & 7;
  const int lrow = lane & 15, kg = lane >> 4;
  const u16* Zb = Zt + (size_t)b * DD * LL;
  f32x4 acc[4][4];
#pragma unroll
  for (int i = 0; i < 4; ++i)
#pragma unroll
    for (int j = 0; j < 4; ++j) acc[i][j] = (f32x4){0.f, 0.f, 0.f, 0.f};
  const int arow = lane >> 2, acol = (lane & 3) * 8;
  for (int k0 = 0; k0 < LL; k0 += 32) {
#pragma unroll
    for (int cc = 0; cc < 2; ++cc) {
      int c = 2 * wave + cc;
      const u16* ga = Wm + (size_t)(tm * 128 + c * 16 + arow) * LL + k0 + acol;
      __builtin_amdgcn_global_load_lds(GPTR(ga), LPTR(Al + c * 512), 16, 0, 0);
      const u16* gb = Zb + (size_t)(tn * 128 + c * 16 + arow) * LL + k0 + acol;
      __builtin_amdgcn_global_load_lds(GPTR(gb), LPTR(Bl + c * 512), 16, 0, 0);
    }
    __syncthreads();
    bf16x8 a2[4], b2[4];
#pragma unroll
    for (int mi = 0; mi < 4; ++mi)
      a2[mi] = __builtin_bit_cast(bf16x8, *(const uint4*)&Al[(wm * 64 + mi * 16 + lrow) * 32 + kg * 8]);
#pragma unroll
    for (int ni = 0; ni < 4; ++ni)
      b2[ni] = __builtin_bit_cast(bf16x8, *(const uint4*)&Bl[(wn * 64 + ni * 16 + lrow) * 32 + kg * 8]);
#pragma unroll
    for (int mi = 0; mi < 4; ++mi)
#pragma unroll
      for (int ni = 0; ni < 4; ++ni)
        acc[mi][ni] = __builtin_amdgcn_mfma_f32_16x16x32_bf16(a2[mi], b2[ni], acc[mi][ni], 0, 0, 0);
    __syncthreads();
  }
#pragma unroll
  for (int ni = 0; ni < 4; ++ni) {
    int c = tn * 128 + wn * 64 + ni * 16 + lrow;
    float sc = S[c], ob = out_b[c];
#pragma unroll
    for (int mi = 0; mi < 4; ++mi)
#pragma unroll
      for (int j = 0; j < 4; ++j) {
        int r = tm * 128 + wm * 64 + mi * 16 + kg * 4 + j;
        out[((size_t)b * LL + r) * DD + c] = acc[mi][ni][j] + conv_b[r] * sc + ob;
      }
  }
}

// ---------------------------------------------------------------------------
extern "C" void kernel_launch(void* const* d_in, const int* in_sizes, int n_in,
                              void* d_out, int out_size, void* d_ws, size_t ws_size,
                              hipStream_t stream) {
  const float* x      = (const float*)d_in[0];
  const float* conv_w = (const float*)d_in[1];
  const float* conv_b = (const float*)d_in[2];
  const float* out_w  = (const float*)d_in[3];
  const float* out_b  = (const float*)d_in[4];
  float* out = (float*)d_out;

  char* ws = (char*)d_ws;
  u16*   W_bf = (u16*)ws;                                // 2 MB
  u16*   weff = (u16*)(ws + (2u << 20));                 // 2 MB
  float* S    = (float*)(ws + (4u << 20));               // 64 KB slot
  u16*   Zt   = (u16*)(ws + (4u << 20) + (1u << 16));    // 32 MB
  u16*   x_bf = (u16*)(ws + (36u << 20) + (1u << 16));   // 32 MB
  const size_t need = (68ull << 20) + (1u << 16);

  hipError_t e0 = hipFuncSetAttribute(reinterpret_cast<const void*>(gemm16<0>),
                                      hipFuncAttributeMaxDynamicSharedMemorySize, 131072);
  hipError_t e1 = hipFuncSetAttribute(reinterpret_cast<const void*>(gemm16<1>),
                                      hipFuncAttributeMaxDynamicSharedMemorySize, 131072);
  const bool use16 = (e0 == hipSuccess) && (e1 == hipSuccess) && (ws_size >= need);

  if (use16) {
    hipLaunchKernelGGL(prep_kernel, dim3(4096), dim3(256), 0, stream,
                       x, conv_w, out_w, x_bf, W_bf, weff, S);
    hipLaunchKernelGGL((gemm16<0>), dim3(256), dim3(1024), 131072, stream,
                       weff, x_bf, (void*)Zt, (const float*)nullptr,
                       (const float*)nullptr, (const float*)nullptr);
    hipLaunchKernelGGL((gemm16<1>), dim3(256), dim3(1024), 131072, stream,
                       W_bf, Zt, (void*)out, conv_b, S, out_b);
  } else {
    hipLaunchKernelGGL(prep_kernel, dim3(2048), dim3(256), 0, stream,
                       x, conv_w, out_w, x_bf, W_bf, weff, S);  // sections 0/1 only
    hipLaunchKernelGGL(gemmA_f32, dim3(64, NB), dim3(256), 0, stream, weff, x, Zt);
    hipLaunchKernelGGL(gemmB2, dim3(64, NB), dim3(256), 0, stream, W_bf, Zt, conv_b, S, out_b, out);
  }
}

// Round 8
// 98.657 us; speedup vs baseline: 1.1523x; 1.1523x over previous
//
#include <hip/hip_runtime.h>
#include <cstdint>

#define LL 1024
#define DD 1024
#define NB 16
#define NHH 8

typedef __bf16 bf16x8 __attribute__((ext_vector_type(8)));
typedef float f32x4 __attribute__((ext_vector_type(4)));
typedef unsigned short u16;

#define GPTR(x) ((const __attribute__((address_space(1))) void*)(x))
#define LPTR(x) ((__attribute__((address_space(3))) void*)(x))
#define BAR()   __builtin_amdgcn_s_barrier()
#define LGKM0() asm volatile("s_waitcnt lgkmcnt(0)" ::: "memory")
#define VMC(N)  asm volatile("s_waitcnt vmcnt(" #N ")" ::: "memory")

static __device__ __forceinline__ u16 f2b(float f) {
  unsigned int u = __float_as_uint(f);
  u += 0x7FFFu + ((u >> 16) & 1u);
  return (u16)(u >> 16);
}

// ---------------------------------------------------------------------------
// Fused prologue: one dispatch, grid-sectioned.
//   blocks [0,1024)      : weff rows  (w_eff = head-sum of out_w, bf16 + S)
//   blocks [1024,2048)   : softmax rows of tril(conv_w) (faithful exp(0) terms)
//   blocks [2048,4096)   : x f32 -> bf16 streaming convert (grid-stride)
// ---------------------------------------------------------------------------
__global__ __launch_bounds__(256) void prep_kernel(const float* __restrict__ x,
                                                   const float* __restrict__ conv_w,
                                                   const float* __restrict__ out_w,
                                                   u16* __restrict__ xb,
                                                   u16* __restrict__ Wb,
                                                   u16* __restrict__ weff,
                                                   float* __restrict__ S) {
  const int blk = blockIdx.x;
  const int t = threadIdx.x;
  __shared__ float red[256];

  if (blk < 1024) {
    const int o = blk;
    const float4* row = (const float4*)(out_w + (size_t)o * (DD * NHH));
    float4 s4 = {0.f, 0.f, 0.f, 0.f};
#pragma unroll
    for (int h = 0; h < NHH; ++h) {
      float4 v = row[h * 256 + t];
      s4.x += v.x; s4.y += v.y; s4.z += v.z; s4.w += v.w;
    }
    ushort4 p;
    p.x = f2b(s4.x); p.y = f2b(s4.y); p.z = f2b(s4.z); p.w = f2b(s4.w);
    *(ushort4*)&weff[(size_t)o * DD + t * 4] = p;
    red[t] = s4.x + s4.y + s4.z + s4.w;
    __syncthreads();
    for (int st = 128; st > 0; st >>= 1) {
      if (t < st) red[t] += red[t + st];
      __syncthreads();
    }
    if (t == 0) S[o] = red[0];
  } else if (blk < 2048) {
    const int f = blk - 1024;
    float z[4];
    float mx = -1e30f;
#pragma unroll
    for (int i = 0; i < 4; ++i) {
      int d = t + i * 256;
      float v = conv_w[(size_t)f * LL + d];
      z[i] = (d <= f) ? v : 0.f;
      mx = fmaxf(mx, z[i]);
    }
    red[t] = mx;
    __syncthreads();
    for (int st = 128; st > 0; st >>= 1) {
      if (t < st) red[t] = fmaxf(red[t], red[t + st]);
      __syncthreads();
    }
    mx = red[0];
    __syncthreads();
    float e[4], s = 0.f;
#pragma unroll
    for (int i = 0; i < 4; ++i) { e[i] = expf(z[i] - mx); s += e[i]; }
    red[t] = s;
    __syncthreads();
    for (int st = 128; st > 0; st >>= 1) {
      if (t < st) red[t] += red[t + st];
      __syncthreads();
    }
    float inv = 1.f / red[0];
#pragma unroll
    for (int i = 0; i < 4; ++i) Wb[(size_t)f * LL + t + i * 256] = f2b(e[i] * inv);
  } else {
    const int n8 = (NB * LL * DD) / 8;
    int i = (blk - 2048) * 256 + t;
    const int stride = 2048 * 256;
    for (; i < n8; i += stride) {
      float4 v0 = ((const float4*)x)[2 * i];
      float4 v1 = ((const float4*)x)[2 * i + 1];
      uint4 p;
      p.x = (unsigned)f2b(v0.x) | ((unsigned)f2b(v0.y) << 16);
      p.y = (unsigned)f2b(v0.z) | ((unsigned)f2b(v0.w) << 16);
      p.z = (unsigned)f2b(v1.x) | ((unsigned)f2b(v1.y) << 16);
      p.w = (unsigned)f2b(v1.z) | ((unsigned)f2b(v1.w) << 16);
      ((uint4*)xb)[i] = p;
    }
  }
}

// ---------------------------------------------------------------------------
// 8-phase 256x256 GEMM (T1+T2+T3+T4+T5), 16x16x32 MFMA, LDS-staged epilogue.
//   A [1024x1024] bf16 K-contig (shared), B [b][1024x1024] bf16 K-contig.
// EPI=0: C bf16 (Zt). EPI=1: C f32 + conv_b[r]*S[c] + out_b[c].
// Stage issue split: B-half after P2 (B fully consumed), A-half after P3
// (A fully consumed) — earliest-legal prefetch, same vmcnt accounting.
// ---------------------------------------------------------------------------
__device__ __forceinline__ void stageHalf(const u16* __restrict__ g, u16* l,
                                          int wave, int lane) {
  const int rlo = lane >> 3;
  const int sl = (lane & 7) ^ rlo;       // pre-swizzled source slot
#pragma unroll
  for (int j = 0; j < 4; ++j) {
    const u16* src = g + (size_t)(j * 64 + wave * 8 + rlo) * 1024 + sl * 8;
    __builtin_amdgcn_global_load_lds(GPTR(src), LPTR(l + j * 4096 + wave * 512), 16, 0, 0);
  }
}

__device__ __forceinline__ bf16x8 ldsRead(const u16* l, int row, int slot) {
  int off = row * 64 + (((slot) ^ (row & 7)) << 3);
  return __builtin_bit_cast(bf16x8, *(const uint4*)(l + off));
}

template <int EPI>
__global__ __launch_bounds__(512, 2) void gemm8(const u16* __restrict__ A,
                                                const u16* __restrict__ Bm,
                                                void* __restrict__ Cout,
                                                const float* __restrict__ conv_b,
                                                const float* __restrict__ S,
                                                const float* __restrict__ out_b) {
  extern __shared__ u16 lds[];
  u16* A0 = lds;
  u16* B0 = lds + 16384;
  u16* A1 = lds + 32768;
  u16* B1 = lds + 49152;

  int bid = blockIdx.x;
  bid = (bid & 7) * 32 + (bid >> 3);          // T1: contiguous chunk per XCD
  const int b = bid >> 4;
  const int tm = (bid >> 2) & 3;
  const int tn = bid & 3;

  const int tid = threadIdx.x, lane = tid & 63, wave = tid >> 6;
  const int wm = wave >> 2, wn = wave & 3;    // 2 x 4 waves
  const int lrow = lane & 15, kg = lane >> 4;

  const u16* Ablk = A + (size_t)(tm * 256) * 1024;
  const u16* Bblk = Bm + (size_t)b * (1024 * 1024) + (size_t)(tn * 256) * 1024;

  f32x4 acc[8][4];
#pragma unroll
  for (int i = 0; i < 8; ++i)
#pragma unroll
    for (int j = 0; j < 4; ++j) acc[i][j] = (f32x4){0.f, 0.f, 0.f, 0.f};

  bf16x8 af[8], b0r[4], b1r[4];

  auto readAfr = [&](const u16* Ab, int mh) {
#pragma unroll
    for (int q = 0; q < 4; ++q)
#pragma unroll
      for (int ks = 0; ks < 2; ++ks)
        af[q * 2 + ks] = ldsRead(Ab, wm * 128 + (mh * 4 + q) * 16 + lrow, kg + 4 * ks);
  };
  auto readBfr = [&](const u16* Bb, int nh, bf16x8* dst) {
#pragma unroll
    for (int n = 0; n < 2; ++n)
#pragma unroll
      for (int ks = 0; ks < 2; ++ks)
        dst[n * 2 + ks] = ldsRead(Bb, wn * 64 + (nh * 2 + n) * 16 + lrow, kg + 4 * ks);
  };
  auto mfmaQuad = [&](int mh, int nh, bf16x8* bfr) {
    __builtin_amdgcn_s_setprio(1);
#pragma unroll
    for (int q = 0; q < 4; ++q)
#pragma unroll
      for (int n = 0; n < 2; ++n)
#pragma unroll
        for (int ks = 0; ks < 2; ++ks)
          acc[mh * 4 + q][nh * 2 + n] = __builtin_amdgcn_mfma_f32_16x16x32_bf16(
              af[q * 2 + ks], bfr[n * 2 + ks], acc[mh * 4 + q][nh * 2 + n], 0, 0, 0);
    __builtin_amdgcn_s_setprio(0);
  };

  // prologue: t0 -> buf0, t1 -> buf1; wait t0 (8 loads of t1 stay in flight)
  stageHalf(Ablk, A0, wave, lane);
  stageHalf(Bblk, B0, wave, lane);
  stageHalf(Ablk + 64, A1, wave, lane);
  stageHalf(Bblk + 64, B1, wave, lane);
  VMC(8);
  BAR();

  for (int i = 0; i < 7; ++i) {
    const int t2 = 2 * i + 2, t3 = 2 * i + 3;
    // ---- tile 2i from buf0 ----
    readAfr(A0, 0); readBfr(B0, 0, b0r); BAR(); LGKM0(); mfmaQuad(0, 0, b0r); BAR();
    readBfr(B0, 1, b1r);                 BAR(); LGKM0(); mfmaQuad(0, 1, b1r); BAR();
    stageHalf(Bblk + t2 * 64, B0, wave, lane);   // B0 consumed (P2 drained+barrier)
    readAfr(A0, 1);                      BAR(); LGKM0(); mfmaQuad(1, 1, b1r); BAR();
    stageHalf(Ablk + t2 * 64, A0, wave, lane);   // A0 consumed (P3 drained+barrier)
    mfmaQuad(1, 0, b0r); VMC(8); BAR();          // tile 2i+1's 8 loads complete
    // ---- tile 2i+1 from buf1 ----
    readAfr(A1, 0); readBfr(B1, 0, b0r); BAR(); LGKM0(); mfmaQuad(0, 0, b0r); BAR();
    readBfr(B1, 1, b1r);                 BAR(); LGKM0(); mfmaQuad(0, 1, b1r); BAR();
    stageHalf(Bblk + t3 * 64, B1, wave, lane);
    readAfr(A1, 1);                      BAR(); LGKM0(); mfmaQuad(1, 1, b1r); BAR();
    stageHalf(Ablk + t3 * 64, A1, wave, lane);
    mfmaQuad(1, 0, b0r); VMC(8); BAR();          // tile 2i+2's 8 loads complete
  }
  // epilogue tiles: 14 (buf0) and 15 (buf1), no staging
  readAfr(A0, 0); readBfr(B0, 0, b0r); BAR(); LGKM0(); mfmaQuad(0, 0, b0r); BAR();
  readBfr(B0, 1, b1r);                 BAR(); LGKM0(); mfmaQuad(0, 1, b1r); BAR();
  readAfr(A0, 1);                      BAR(); LGKM0(); mfmaQuad(1, 1, b1r); BAR();
  mfmaQuad(1, 0, b0r); VMC(0); BAR();
  readAfr(A1, 0); readBfr(B1, 0, b0r); BAR(); LGKM0(); mfmaQuad(0, 0, b0r); BAR();
  readBfr(B1, 1, b1r);                 BAR(); LGKM0(); mfmaQuad(0, 1, b1r); BAR();
  readAfr(A1, 1);                      BAR(); LGKM0(); mfmaQuad(1, 1, b1r); BAR();
  mfmaQuad(1, 0, b0r);

  // all waves' ds_reads are complete before this barrier (each wave LGKM0'd
  // before its final MFMAs) -> safe to reuse the LDS for the epilogue.
  BAR();

  if constexpr (EPI == 0) {
    // acc -> LDS (256x256 bf16 = 128 KiB, bank-swizzled), then coalesced store
    u16* E = lds;
#pragma unroll
    for (int mi = 0; mi < 8; ++mi)
#pragma unroll
      for (int ni = 0; ni < 4; ++ni)
#pragma unroll
        for (int j = 0; j < 4; ++j) {
          int r = wm * 128 + mi * 16 + kg * 4 + j;
          int c = wn * 64 + ni * 16 + lrow;
          E[r * 256 + (c ^ (((r >> 2) & 3) << 4))] = f2b(acc[mi][ni][j]);
        }
    __syncthreads();
    u16* Cb = (u16*)Cout + (size_t)b * (1024 * 1024) + (size_t)(tm * 256) * 1024 + tn * 256;
#pragma unroll
    for (int i = 0; i < 16; ++i) {
      int r = i * 16 + (tid >> 5);
      int cl = (tid & 31) * 8;
      uint4 v = *(const uint4*)&E[r * 256 + (cl ^ (((r >> 2) & 3) << 4))];
      *(uint4*)&Cb[(size_t)r * 1024 + cl] = v;
    }
  } else {
    // two 128-row halves through LDS (128 KiB f32 each), bias fused at write
    float* Ef = (float*)lds;
    float* Cf = (float*)Cout + (size_t)b * (1024 * 1024) + (size_t)(tm * 256) * 1024 + tn * 256;
#pragma unroll
    for (int h = 0; h < 2; ++h) {
      if (h) __syncthreads();  // half-0 readers done before overwrite
#pragma unroll
      for (int mi2 = 0; mi2 < 4; ++mi2) {
        int mi = 4 * h + mi2;
#pragma unroll
        for (int ni = 0; ni < 4; ++ni) {
          int c = wn * 64 + ni * 16 + lrow;
          float sc = S[tn * 256 + c], ob = out_b[tn * 256 + c];
#pragma unroll
          for (int j = 0; j < 4; ++j) {
            int li = wm * 64 + mi2 * 16 + kg * 4 + j;
            int rg = tm * 256 + wm * 128 + mi * 16 + kg * 4 + j;
            Ef[li * 256 + (c ^ ((li & 4) << 2))] = acc[mi][ni][j] + conv_b[rg] * sc + ob;
          }
        }
      }
      __syncthreads();
#pragma unroll
      for (int i = 0; i < 16; ++i) {
        int li = i * 8 + (tid >> 6);
        int cl = (tid & 63) * 4;
        float4 v = *(const float4*)&Ef[li * 256 + (cl ^ ((li & 4) << 2))];
        int rblk = (li >> 6) * 128 + h * 64 + (li & 63);
        *(float4*)&Cf[(size_t)rblk * 1024 + cl] = v;
      }
    }
  }
}

// ---------------------------------------------------------------------------
// Fallback 128^2 2-phase kernels (used only if 128KB-LDS attr or ws fails)
// ---------------------------------------------------------------------------
__global__ __launch_bounds__(256) void gemmA_f32(const u16* __restrict__ weff,
                                                 const float* __restrict__ x,
                                                 u16* __restrict__ Zt) {
  __shared__ u16 Al[128 * 32];
  __shared__ u16 Bl[128 * 32];
  const int b = blockIdx.y;
  const int tid = threadIdx.x, lane = tid & 63, wave = tid >> 6;
  const int wm = wave >> 1, wn = wave & 1;
  const int tm = blockIdx.x >> 3, tn = blockIdx.x & 7;
  const int lrow = lane & 15, kg = lane >> 4;
  const float* xbp = x + (size_t)b * LL * DD;
  f32x4 acc[4][4];
#pragma unroll
  for (int i = 0; i < 4; ++i)
#pragma unroll
    for (int j = 0; j < 4; ++j) acc[i][j] = (f32x4){0.f, 0.f, 0.f, 0.f};
  const int brow = tid >> 2, bcol = (tid & 3) * 8;
  const int arow = lane >> 2, acol = (lane & 3) * 8;
  for (int k0 = 0; k0 < DD; k0 += 32) {
#pragma unroll
    for (int cc = 0; cc < 2; ++cc) {
      int c = 2 * wave + cc;
      const u16* g = weff + (size_t)(tm * 128 + c * 16 + arow) * DD + k0 + acol;
      __builtin_amdgcn_global_load_lds(GPTR(g), LPTR(Al + c * 512), 16, 0, 0);
    }
#pragma unroll
    for (int ch = 0; ch < 2; ++ch) {
      const float* gp = xbp + (size_t)(tn * 128 + ch * 64 + brow) * DD + k0 + bcol;
      float4 v0 = *(const float4*)gp;
      float4 v1 = *(const float4*)(gp + 4);
      uint4 p;
      p.x = (unsigned)f2b(v0.x) | ((unsigned)f2b(v0.y) << 16);
      p.y = (unsigned)f2b(v0.z) | ((unsigned)f2b(v0.w) << 16);
      p.z = (unsigned)f2b(v1.x) | ((unsigned)f2b(v1.y) << 16);
      p.w = (unsigned)f2b(v1.z) | ((unsigned)f2b(v1.w) << 16);
      *(uint4*)&Bl[(ch * 64 + brow) * 32 + bcol] = p;
    }
    __syncthreads();
    bf16x8 a2[4], b2[4];
#pragma unroll
    for (int mi = 0; mi < 4; ++mi)
      a2[mi] = __builtin_bit_cast(bf16x8, *(const uint4*)&Al[(wm * 64 + mi * 16 + lrow) * 32 + kg * 8]);
#pragma unroll
    for (int ni = 0; ni < 4; ++ni)
      b2[ni] = __builtin_bit_cast(bf16x8, *(const uint4*)&Bl[(wn * 64 + ni * 16 + lrow) * 32 + kg * 8]);
#pragma unroll
    for (int mi = 0; mi < 4; ++mi)
#pragma unroll
      for (int ni = 0; ni < 4; ++ni)
        acc[mi][ni] = __builtin_amdgcn_mfma_f32_16x16x32_bf16(a2[mi], b2[ni], acc[mi][ni], 0, 0, 0);
    __syncthreads();
  }
  u16* Zb = Zt + (size_t)b * DD * LL;
#pragma unroll
  for (int mi = 0; mi < 4; ++mi)
#pragma unroll
    for (int ni = 0; ni < 4; ++ni)
#pragma unroll
      for (int j = 0; j < 4; ++j) {
        int r = tm * 128 + wm * 64 + mi * 16 + kg * 4 + j;
        int c = tn * 128 + wn * 64 + ni * 16 + lrow;
        Zb[(size_t)r * LL + c] = f2b(acc[mi][ni][j]);
      }
}

__global__ __launch_bounds__(256) void gemmB2(const u16* __restrict__ Wm,
                                              const u16* __restrict__ Zt,
                                              const float* __restrict__ conv_b,
                                              const float* __restrict__ S,
                                              const float* __restrict__ out_b,
                                              float* __restrict__ out) {
  __shared__ u16 Al[128 * 32];
  __shared__ u16 Bl[128 * 32];
  const int b = blockIdx.y;
  const int tid = threadIdx.x, lane = tid & 63, wave = tid >> 6;
  const int wm = wave >> 1, wn = wave & 1;
  const int tm = blockIdx.x >> 3, tn = blockIdx.x & 7;
  const int lrow = lane & 15, kg = lane >> 4;
  const u16* Zb = Zt + (size_t)b * DD * LL;
  f32x4 acc[4][4];
#pragma unroll
  for (int i = 0; i < 4; ++i)
#pragma unroll
    for (int j = 0; j < 4; ++j) acc[i][j] = (f32x4){0.f, 0.f, 0.f, 0.f};
  const int arow = lane >> 2, acol = (lane & 3) * 8;
  for (int k0 = 0; k0 < LL; k0 += 32) {
#pragma unroll
    for (int cc = 0; cc < 2; ++cc) {
      int c = 2 * wave + cc;
      const u16* ga = Wm + (size_t)(tm * 128 + c * 16 + arow) * LL + k0 + acol;
      __builtin_amdgcn_global_load_lds(GPTR(ga), LPTR(Al + c * 512), 16, 0, 0);
      const u16* gb = Zb + (size_t)(tn * 128 + c * 16 + arow) * LL + k0 + acol;
      __builtin_amdgcn_global_load_lds(GPTR(gb), LPTR(Bl + c * 512), 16, 0, 0);
    }
    __syncthreads();
    bf16x8 a2[4], b2[4];
#pragma unroll
    for (int mi = 0; mi < 4; ++mi)
      a2[mi] = __builtin_bit_cast(bf16x8, *(const uint4*)&Al[(wm * 64 + mi * 16 + lrow) * 32 + kg * 8]);
#pragma unroll
    for (int ni = 0; ni < 4; ++ni)
      b2[ni] = __builtin_bit_cast(bf16x8, *(const uint4*)&Bl[(wn * 64 + ni * 16 + lrow) * 32 + kg * 8]);
#pragma unroll
    for (int mi = 0; mi < 4; ++mi)
#pragma unroll
      for (int ni = 0; ni < 4; ++ni)
        acc[mi][ni] = __builtin_amdgcn_mfma_f32_16x16x32_bf16(a2[mi], b2[ni], acc[mi][ni], 0, 0, 0);
    __syncthreads();
  }
#pragma unroll
  for (int ni = 0; ni < 4; ++ni) {
    int c = tn * 128 + wn * 64 + ni * 16 + lrow;
    float sc = S[c], ob = out_b[c];
#pragma unroll
    for (int mi = 0; mi < 4; ++mi)
#pragma unroll
      for (int j = 0; j < 4; ++j) {
        int r = tm * 128 + wm * 64 + mi * 16 + kg * 4 + j;
        out[((size_t)b * LL + r) * DD + c] = acc[mi][ni][j] + conv_b[r] * sc + ob;
      }
  }
}

// ---------------------------------------------------------------------------
extern "C" void kernel_launch(void* const* d_in, const int* in_sizes, int n_in,
                              void* d_out, int out_size, void* d_ws, size_t ws_size,
                              hipStream_t stream) {
  const float* x      = (const float*)d_in[0];
  const float* conv_w = (const float*)d_in[1];
  const float* conv_b = (const float*)d_in[2];
  const float* out_w  = (const float*)d_in[3];
  const float* out_b  = (const float*)d_in[4];
  float* out = (float*)d_out;

  char* ws = (char*)d_ws;
  u16*   W_bf = (u16*)ws;                                // 2 MB
  u16*   weff = (u16*)(ws + (2u << 20));                 // 2 MB
  float* S    = (float*)(ws + (4u << 20));               // 64 KB slot
  u16*   Zt   = (u16*)(ws + (4u << 20) + (1u << 16));    // 32 MB
  u16*   x_bf = (u16*)(ws + (36u << 20) + (1u << 16));   // 32 MB
  const size_t need = (68ull << 20) + (1u << 16);

  hipError_t e0 = hipFuncSetAttribute(reinterpret_cast<const void*>(gemm8<0>),
                                      hipFuncAttributeMaxDynamicSharedMemorySize, 131072);
  hipError_t e1 = hipFuncSetAttribute(reinterpret_cast<const void*>(gemm8<1>),
                                      hipFuncAttributeMaxDynamicSharedMemorySize, 131072);
  const bool use8 = (e0 == hipSuccess) && (e1 == hipSuccess) && (ws_size >= need);

  if (use8) {
    hipLaunchKernelGGL(prep_kernel, dim3(4096), dim3(256), 0, stream,
                       x, conv_w, out_w, x_bf, W_bf, weff, S);
    hipLaunchKernelGGL((gemm8<0>), dim3(256), dim3(512), 131072, stream,
                       weff, x_bf, (void*)Zt, (const float*)nullptr,
                       (const float*)nullptr, (const float*)nullptr);
    hipLaunchKernelGGL((gemm8<1>), dim3(256), dim3(512), 131072, stream,
                       W_bf, Zt, (void*)out, conv_b, S, out_b);
  } else {
    hipLaunchKernelGGL(prep_kernel, dim3(2048), dim3(256), 0, stream,
                       x, conv_w, out_w, x_bf, W_bf, weff, S);  // sections 0/1 only
    hipLaunchKernelGGL(gemmA_f32, dim3(64, NB), dim3(256), 0, stream, weff, x, Zt);
    hipLaunchKernelGGL(gemmB2, dim3(64, NB), dim3(256), 0, stream, W_bf, Zt, conv_b, S, out_b, out);
  }
}

// Round 10
// 97.551 us; speedup vs baseline: 1.1653x; 1.0113x over previous
//
#include <hip/hip_runtime.h>
#include <cstdint>

#define LL 1024
#define DD 1024
#define NB 16
#define NHH 8

typedef __bf16 bf16x8 __attribute__((ext_vector_type(8)));
typedef float f32x4 __attribute__((ext_vector_type(4)));
typedef unsigned short u16;

#define GPTR(x) ((const __attribute__((address_space(1))) void*)(x))
#define LPTR(x) ((__attribute__((address_space(3))) void*)(x))
#define BAR()   __builtin_amdgcn_s_barrier()
#define LGKM0() asm volatile("s_waitcnt lgkmcnt(0)" ::: "memory")
#define VMC(N)  asm volatile("s_waitcnt vmcnt(" #N ")" ::: "memory")

static __device__ __forceinline__ u16 f2b(float f) {
  unsigned int u = __float_as_uint(f);
  u += 0x7FFFu + ((u >> 16) & 1u);
  return (u16)(u >> 16);
}

// ---------------------------------------------------------------------------
// Fused prologue: one dispatch, grid-sectioned.
//   blocks [0,1024)      : weff rows  (w_eff = head-sum of out_w, bf16 + S)
//   blocks [1024,2048)   : softmax rows of tril(conv_w) (faithful exp(0) terms)
//   blocks [2048,4096)   : x f32 -> bf16 streaming convert (grid-stride)
// ---------------------------------------------------------------------------
__global__ __launch_bounds__(256) void prep_kernel(const float* __restrict__ x,
                                                   const float* __restrict__ conv_w,
                                                   const float* __restrict__ out_w,
                                                   u16* __restrict__ xb,
                                                   u16* __restrict__ Wb,
                                                   u16* __restrict__ weff,
                                                   float* __restrict__ S) {
  const int blk = blockIdx.x;
  const int t = threadIdx.x;
  __shared__ float red[256];

  if (blk < 1024) {
    const int o = blk;
    const float4* row = (const float4*)(out_w + (size_t)o * (DD * NHH));
    float4 s4 = {0.f, 0.f, 0.f, 0.f};
#pragma unroll
    for (int h = 0; h < NHH; ++h) {
      float4 v = row[h * 256 + t];
      s4.x += v.x; s4.y += v.y; s4.z += v.z; s4.w += v.w;
    }
    ushort4 p;
    p.x = f2b(s4.x); p.y = f2b(s4.y); p.z = f2b(s4.z); p.w = f2b(s4.w);
    *(ushort4*)&weff[(size_t)o * DD + t * 4] = p;
    red[t] = s4.x + s4.y + s4.z + s4.w;
    __syncthreads();
    for (int st = 128; st > 0; st >>= 1) {
      if (t < st) red[t] += red[t + st];
      __syncthreads();
    }
    if (t == 0) S[o] = red[0];
  } else if (blk < 2048) {
    const int f = blk - 1024;
    float z[4];
    float mx = -1e30f;
#pragma unroll
    for (int i = 0; i < 4; ++i) {
      int d = t + i * 256;
      float v = conv_w[(size_t)f * LL + d];
      z[i] = (d <= f) ? v : 0.f;
      mx = fmaxf(mx, z[i]);
    }
    red[t] = mx;
    __syncthreads();
    for (int st = 128; st > 0; st >>= 1) {
      if (t < st) red[t] = fmaxf(red[t], red[t + st]);
      __syncthreads();
    }
    mx = red[0];
    __syncthreads();
    float e[4], s = 0.f;
#pragma unroll
    for (int i = 0; i < 4; ++i) { e[i] = expf(z[i] - mx); s += e[i]; }
    red[t] = s;
    __syncthreads();
    for (int st = 128; st > 0; st >>= 1) {
      if (t < st) red[t] += red[t + st];
      __syncthreads();
    }
    float inv = 1.f / red[0];
#pragma unroll
    for (int i = 0; i < 4; ++i) Wb[(size_t)f * LL + t + i * 256] = f2b(e[i] * inv);
  } else {
    const int n8 = (NB * LL * DD) / 8;
    int i = (blk - 2048) * 256 + t;
    const int stride = 2048 * 256;
    for (; i < n8; i += stride) {
      float4 v0 = ((const float4*)x)[2 * i];
      float4 v1 = ((const float4*)x)[2 * i + 1];
      uint4 p;
      p.x = (unsigned)f2b(v0.x) | ((unsigned)f2b(v0.y) << 16);
      p.y = (unsigned)f2b(v0.z) | ((unsigned)f2b(v0.w) << 16);
      p.z = (unsigned)f2b(v1.x) | ((unsigned)f2b(v1.y) << 16);
      p.w = (unsigned)f2b(v1.z) | ((unsigned)f2b(v1.w) << 16);
      ((uint4*)xb)[i] = p;
    }
  }
}

// ---------------------------------------------------------------------------
// 8-phase 256x256 GEMM (T1+T2+T3+T4+T5), 16x16x32 MFMA, LDS-staged epilogue.
//   A [1024x1024] bf16 K-contig (shared), B [b][1024x1024] bf16 K-contig.
// EPI=0: C bf16 (Zt). EPI=1: C f32 + conv_b[r]*S[c] + out_b[c].
// Stage issue split: B-half after P2 (B fully consumed), A-half after P3
// (A fully consumed). The LGKM0() "memory"-clobber asm after each barrier is
// load-bearing: it is the COMPILER fence that keeps global_load_lds staging
// from hoisting above pending ds_reads (raw s_barrier is not an LLVM memory
// barrier — round-9 lesson).
// ---------------------------------------------------------------------------
__device__ __forceinline__ void stageHalf(const u16* __restrict__ g, u16* l,
                                          int wave, int lane) {
  const int rlo = lane >> 3;
  const int sl = (lane & 7) ^ rlo;       // pre-swizzled source slot
#pragma unroll
  for (int j = 0; j < 4; ++j) {
    const u16* src = g + (size_t)(j * 64 + wave * 8 + rlo) * 1024 + sl * 8;
    __builtin_amdgcn_global_load_lds(GPTR(src), LPTR(l + j * 4096 + wave * 512), 16, 0, 0);
  }
}

__device__ __forceinline__ bf16x8 ldsRead(const u16* l, int row, int slot) {
  int off = row * 64 + (((slot) ^ (row & 7)) << 3);
  return __builtin_bit_cast(bf16x8, *(const uint4*)(l + off));
}

template <int EPI>
__global__ __launch_bounds__(512, 2) void gemm8(const u16* __restrict__ A,
                                                const u16* __restrict__ Bm,
                                                void* __restrict__ Cout,
                                                const float* __restrict__ conv_b,
                                                const float* __restrict__ S,
                                                const float* __restrict__ out_b) {
  extern __shared__ u16 lds[];
  u16* A0 = lds;
  u16* B0 = lds + 16384;
  u16* A1 = lds + 32768;
  u16* B1 = lds + 49152;

  int bid = blockIdx.x;
  bid = (bid & 7) * 32 + (bid >> 3);          // T1: contiguous chunk per XCD
  const int b = bid >> 4;
  const int tm = (bid >> 2) & 3;
  const int tn = bid & 3;

  const int tid = threadIdx.x, lane = tid & 63, wave = tid >> 6;
  const int wm = wave >> 2, wn = wave & 3;    // 2 x 4 waves
  const int lrow = lane & 15, kg = lane >> 4;

  const u16* Ablk = A + (size_t)(tm * 256) * 1024;
  const u16* Bblk = Bm + (size_t)b * (1024 * 1024) + (size_t)(tn * 256) * 1024;

  f32x4 acc[8][4];
#pragma unroll
  for (int i = 0; i < 8; ++i)
#pragma unroll
    for (int j = 0; j < 4; ++j) acc[i][j] = (f32x4){0.f, 0.f, 0.f, 0.f};

  bf16x8 af[8], b0r[4], b1r[4];

  auto readAfr = [&](const u16* Ab, int mh) {
#pragma unroll
    for (int q = 0; q < 4; ++q)
#pragma unroll
      for (int ks = 0; ks < 2; ++ks)
        af[q * 2 + ks] = ldsRead(Ab, wm * 128 + (mh * 4 + q) * 16 + lrow, kg + 4 * ks);
  };
  auto readBfr = [&](const u16* Bb, int nh, bf16x8* dst) {
#pragma unroll
    for (int n = 0; n < 2; ++n)
#pragma unroll
      for (int ks = 0; ks < 2; ++ks)
        dst[n * 2 + ks] = ldsRead(Bb, wn * 64 + (nh * 2 + n) * 16 + lrow, kg + 4 * ks);
  };
  auto mfmaQuad = [&](int mh, int nh, bf16x8* bfr) {
    __builtin_amdgcn_s_setprio(1);
#pragma unroll
    for (int q = 0; q < 4; ++q)
#pragma unroll
      for (int n = 0; n < 2; ++n)
#pragma unroll
        for (int ks = 0; ks < 2; ++ks)
          acc[mh * 4 + q][nh * 2 + n] = __builtin_amdgcn_mfma_f32_16x16x32_bf16(
              af[q * 2 + ks], bfr[n * 2 + ks], acc[mh * 4 + q][nh * 2 + n], 0, 0, 0);
    __builtin_amdgcn_s_setprio(0);
  };

  // prologue: t0 -> buf0, t1 -> buf1; wait t0 (8 loads of t1 stay in flight)
  stageHalf(Ablk, A0, wave, lane);
  stageHalf(Bblk, B0, wave, lane);
  stageHalf(Ablk + 64, A1, wave, lane);
  stageHalf(Bblk + 64, B1, wave, lane);
  VMC(8);
  BAR();

  for (int i = 0; i < 7; ++i) {
    const int t2 = 2 * i + 2, t3 = 2 * i + 3;
    // ---- tile 2i from buf0 ----
    readAfr(A0, 0); readBfr(B0, 0, b0r); BAR(); LGKM0(); mfmaQuad(0, 0, b0r); BAR();
    readBfr(B0, 1, b1r);                 BAR(); LGKM0(); mfmaQuad(0, 1, b1r); BAR();
    stageHalf(Bblk + t2 * 64, B0, wave, lane);   // B0 consumed (P2 drained+barrier)
    readAfr(A0, 1);                      BAR(); LGKM0(); mfmaQuad(1, 1, b1r); BAR();
    stageHalf(Ablk + t2 * 64, A0, wave, lane);   // A0 consumed (P3 drained+barrier)
    mfmaQuad(1, 0, b0r); VMC(8); BAR();          // tile 2i+1's 8 loads complete
    // ---- tile 2i+1 from buf1 ----
    readAfr(A1, 0); readBfr(B1, 0, b0r); BAR(); LGKM0(); mfmaQuad(0, 0, b0r); BAR();
    readBfr(B1, 1, b1r);                 BAR(); LGKM0(); mfmaQuad(0, 1, b1r); BAR();
    stageHalf(Bblk + t3 * 64, B1, wave, lane);
    readAfr(A1, 1);                      BAR(); LGKM0(); mfmaQuad(1, 1, b1r); BAR();
    stageHalf(Ablk + t3 * 64, A1, wave, lane);
    mfmaQuad(1, 0, b0r); VMC(8); BAR();          // tile 2i+2's 8 loads complete
  }
  // epilogue tiles: 14 (buf0) and 15 (buf1), no staging
  readAfr(A0, 0); readBfr(B0, 0, b0r); BAR(); LGKM0(); mfmaQuad(0, 0, b0r); BAR();
  readBfr(B0, 1, b1r);                 BAR(); LGKM0(); mfmaQuad(0, 1, b1r); BAR();
  readAfr(A0, 1);                      BAR(); LGKM0(); mfmaQuad(1, 1, b1r); BAR();
  mfmaQuad(1, 0, b0r); VMC(0); BAR();
  readAfr(A1, 0); readBfr(B1, 0, b0r); BAR(); LGKM0(); mfmaQuad(0, 0, b0r); BAR();
  readBfr(B1, 1, b1r);                 BAR(); LGKM0(); mfmaQuad(0, 1, b1r); BAR();
  readAfr(A1, 1);                      BAR(); LGKM0(); mfmaQuad(1, 1, b1r); BAR();
  mfmaQuad(1, 0, b0r);

  // all waves' ds_reads are complete before this barrier (each wave LGKM0'd
  // before its final MFMAs) -> safe to reuse the LDS for the epilogue.
  BAR();

  if constexpr (EPI == 0) {
    // acc -> LDS (256x256 bf16 = 128 KiB, bank-swizzled), then coalesced store
    u16* E = lds;
#pragma unroll
    for (int mi = 0; mi < 8; ++mi)
#pragma unroll
      for (int ni = 0; ni < 4; ++ni)
#pragma unroll
        for (int j = 0; j < 4; ++j) {
          int r = wm * 128 + mi * 16 + kg * 4 + j;
          int c = wn * 64 + ni * 16 + lrow;
          E[r * 256 + (c ^ (((r >> 2) & 3) << 4))] = f2b(acc[mi][ni][j]);
        }
    __syncthreads();
    u16* Cb = (u16*)Cout + (size_t)b * (1024 * 1024) + (size_t)(tm * 256) * 1024 + tn * 256;
#pragma unroll
    for (int i = 0; i < 16; ++i) {
      int r = i * 16 + (tid >> 5);
      int cl = (tid & 31) * 8;
      uint4 v = *(const uint4*)&E[r * 256 + (cl ^ (((r >> 2) & 3) << 4))];
      *(uint4*)&Cb[(size_t)r * 1024 + cl] = v;
    }
  } else {
    // two 128-row halves through LDS (128 KiB f32 each), bias fused at write
    float* Ef = (float*)lds;
    float* Cf = (float*)Cout + (size_t)b * (1024 * 1024) + (size_t)(tm * 256) * 1024 + tn * 256;
#pragma unroll
    for (int h = 0; h < 2; ++h) {
      if (h) __syncthreads();  // half-0 readers done before overwrite
#pragma unroll
      for (int mi2 = 0; mi2 < 4; ++mi2) {
        int mi = 4 * h + mi2;
#pragma unroll
        for (int ni = 0; ni < 4; ++ni) {
          int c = wn * 64 + ni * 16 + lrow;
          float sc = S[tn * 256 + c], ob = out_b[tn * 256 + c];
#pragma unroll
          for (int j = 0; j < 4; ++j) {
            int li = wm * 64 + mi2 * 16 + kg * 4 + j;
            int rg = tm * 256 + wm * 128 + mi * 16 + kg * 4 + j;
            Ef[li * 256 + (c ^ ((li & 4) << 2))] = acc[mi][ni][j] + conv_b[rg] * sc + ob;
          }
        }
      }
      __syncthreads();
#pragma unroll
      for (int i = 0; i < 16; ++i) {
        int li = i * 8 + (tid >> 6);
        int cl = (tid & 63) * 4;
        float4 v = *(const float4*)&Ef[li * 256 + (cl ^ ((li & 4) << 2))];
        int rblk = (li >> 6) * 128 + h * 64 + (li & 63);
        *(float4*)&Cf[(size_t)rblk * 1024 + cl] = v;
      }
    }
  }
}

// ---------------------------------------------------------------------------
// Fallback 128^2 2-phase kernels (used only if 128KB-LDS attr or ws fails)
// ---------------------------------------------------------------------------
__global__ __launch_bounds__(256) void gemmA_f32(const u16* __restrict__ weff,
                                                 const float* __restrict__ x,
                                                 u16* __restrict__ Zt) {
  __shared__ u16 Al[128 * 32];
  __shared__ u16 Bl[128 * 32];
  const int b = blockIdx.y;
  const int tid = threadIdx.x, lane = tid & 63, wave = tid >> 6;
  const int wm = wave >> 1, wn = wave & 1;
  const int tm = blockIdx.x >> 3, tn = blockIdx.x & 7;
  const int lrow = lane & 15, kg = lane >> 4;
  const float* xbp = x + (size_t)b * LL * DD;
  f32x4 acc[4][4];
#pragma unroll
  for (int i = 0; i < 4; ++i)
#pragma unroll
    for (int j = 0; j < 4; ++j) acc[i][j] = (f32x4){0.f, 0.f, 0.f, 0.f};
  const int brow = tid >> 2, bcol = (tid & 3) * 8;
  const int arow = lane >> 2, acol = (lane & 3) * 8;
  for (int k0 = 0; k0 < DD; k0 += 32) {
#pragma unroll
    for (int cc = 0; cc < 2; ++cc) {
      int c = 2 * wave + cc;
      const u16* g = weff + (size_t)(tm * 128 + c * 16 + arow) * DD + k0 + acol;
      __builtin_amdgcn_global_load_lds(GPTR(g), LPTR(Al + c * 512), 16, 0, 0);
    }
#pragma unroll
    for (int ch = 0; ch < 2; ++ch) {
      const float* gp = xbp + (size_t)(tn * 128 + ch * 64 + brow) * DD + k0 + bcol;
      float4 v0 = *(const float4*)gp;
      float4 v1 = *(const float4*)(gp + 4);
      uint4 p;
      p.x = (unsigned)f2b(v0.x) | ((unsigned)f2b(v0.y) << 16);
      p.y = (unsigned)f2b(v0.z) | ((unsigned)f2b(v0.w) << 16);
      p.z = (unsigned)f2b(v1.x) | ((unsigned)f2b(v1.y) << 16);
      p.w = (unsigned)f2b(v1.z) | ((unsigned)f2b(v1.w) << 16);
      *(uint4*)&Bl[(ch * 64 + brow) * 32 + bcol] = p;
    }
    __syncthreads();
    bf16x8 a2[4], b2[4];
#pragma unroll
    for (int mi = 0; mi < 4; ++mi)
      a2[mi] = __builtin_bit_cast(bf16x8, *(const uint4*)&Al[(wm * 64 + mi * 16 + lrow) * 32 + kg * 8]);
#pragma unroll
    for (int ni = 0; ni < 4; ++ni)
      b2[ni] = __builtin_bit_cast(bf16x8, *(const uint4*)&Bl[(wn * 64 + ni * 16 + lrow) * 32 + kg * 8]);
#pragma unroll
    for (int mi = 0; mi < 4; ++mi)
#pragma unroll
      for (int ni = 0; ni < 4; ++ni)
        acc[mi][ni] = __builtin_amdgcn_mfma_f32_16x16x32_bf16(a2[mi], b2[ni], acc[mi][ni], 0, 0, 0);
    __syncthreads();
  }
  u16* Zb = Zt + (size_t)b * DD * LL;
#pragma unroll
  for (int mi = 0; mi < 4; ++mi)
#pragma unroll
    for (int ni = 0; ni < 4; ++ni)
#pragma unroll
      for (int j = 0; j < 4; ++j) {
        int r = tm * 128 + wm * 64 + mi * 16 + kg * 4 + j;
        int c = tn * 128 + wn * 64 + ni * 16 + lrow;
        Zb[(size_t)r * LL + c] = f2b(acc[mi][ni][j]);
      }
}

__global__ __launch_bounds__(256) void gemmB2(const u16* __restrict__ Wm,
                                              const u16* __restrict__ Zt,
                                              const float* __restrict__ conv_b,
                                              const float* __restrict__ S,
                                              const float* __restrict__ out_b,
                                              float* __restrict__ out) {
  __shared__ u16 Al[128 * 32];
  __shared__ u16 Bl[128 * 32];
  const int b = blockIdx.y;
  const int tid = threadIdx.x, lane = tid & 63, wave = tid >> 6;
  const int wm = wave >> 1, wn = wave & 1;
  const int tm = blockIdx.x >> 3, tn = blockIdx.x & 7;
  const int lrow = lane & 15, kg = lane >> 4;
  const u16* Zb = Zt + (size_t)b * DD * LL;
  f32x4 acc[4][4];
#pragma unroll
  for (int i = 0; i < 4; ++i)
#pragma unroll
    for (int j = 0; j < 4; ++j) acc[i][j] = (f32x4){0.f, 0.f, 0.f, 0.f};
  const int arow = lane >> 2, acol = (lane & 3) * 8;
  for (int k0 = 0; k0 < LL; k0 += 32) {
#pragma unroll
    for (int cc = 0; cc < 2; ++cc) {
      int c = 2 * wave + cc;
      const u16* ga = Wm + (size_t)(tm * 128 + c * 16 + arow) * LL + k0 + acol;
      __builtin_amdgcn_global_load_lds(GPTR(ga), LPTR(Al + c * 512), 16, 0, 0);
      const u16* gb = Zb + (size_t)(tn * 128 + c * 16 + arow) * LL + k0 + acol;
      __builtin_amdgcn_global_load_lds(GPTR(gb), LPTR(Bl + c * 512), 16, 0, 0);
    }
    __syncthreads();
    bf16x8 a2[4], b2[4];
#pragma unroll
    for (int mi = 0; mi < 4; ++mi)
      a2[mi] = __builtin_bit_cast(bf16x8, *(const uint4*)&Al[(wm * 64 + mi * 16 + lrow) * 32 + kg * 8]);
#pragma unroll
    for (int ni = 0; ni < 4; ++ni)
      b2[ni] = __builtin_bit_cast(bf16x8, *(const uint4*)&Bl[(wn * 64 + ni * 16 + lrow) * 32 + kg * 8]);
#pragma unroll
    for (int mi = 0; mi < 4; ++mi)
#pragma unroll
      for (int ni = 0; ni < 4; ++ni)
        acc[mi][ni] = __builtin_amdgcn_mfma_f32_16x16x32_bf16(a2[mi], b2[ni], acc[mi][ni], 0, 0, 0);
    __syncthreads();
  }
#pragma unroll
  for (int ni = 0; ni < 4; ++ni) {
    int c = tn * 128 + wn * 64 + ni * 16 + lrow;
    float sc = S[c], ob = out_b[c];
#pragma unroll
    for (int mi = 0; mi < 4; ++mi)
#pragma unroll
      for (int j = 0; j < 4; ++j) {
        int r = tm * 128 + wm * 64 + mi * 16 + kg * 4 + j;
        out[((size_t)b * LL + r) * DD + c] = acc[mi][ni][j] + conv_b[r] * sc + ob;
      }
  }
}

// ---------------------------------------------------------------------------
extern "C" void kernel_launch(void* const* d_in, const int* in_sizes, int n_in,
                              void* d_out, int out_size, void* d_ws, size_t ws_size,
                              hipStream_t stream) {
  const float* x      = (const float*)d_in[0];
  const float* conv_w = (const float*)d_in[1];
  const float* conv_b = (const float*)d_in[2];
  const float* out_w  = (const float*)d_in[3];
  const float* out_b  = (const float*)d_in[4];
  float* out = (float*)d_out;

  char* ws = (char*)d_ws;
  u16*   W_bf = (u16*)ws;                                // 2 MB
  u16*   weff = (u16*)(ws + (2u << 20));                 // 2 MB
  float* S    = (float*)(ws + (4u << 20));               // 64 KB slot
  u16*   Zt   = (u16*)(ws + (4u << 20) + (1u << 16));    // 32 MB
  u16*   x_bf = (u16*)(ws + (36u << 20) + (1u << 16));   // 32 MB
  const size_t need = (68ull << 20) + (1u << 16);

  hipError_t e0 = hipFuncSetAttribute(reinterpret_cast<const void*>(gemm8<0>),
                                      hipFuncAttributeMaxDynamicSharedMemorySize, 131072);
  hipError_t e1 = hipFuncSetAttribute(reinterpret_cast<const void*>(gemm8<1>),
                                      hipFuncAttributeMaxDynamicSharedMemorySize, 131072);
  const bool use8 = (e0 == hipSuccess) && (e1 == hipSuccess) && (ws_size >= need);

  if (use8) {
    hipLaunchKernelGGL(prep_kernel, dim3(4096), dim3(256), 0, stream,
                       x, conv_w, out_w, x_bf, W_bf, weff, S);
    hipLaunchKernelGGL((gemm8<0>), dim3(256), dim3(512), 131072, stream,
                       weff, x_bf, (void*)Zt, (const float*)nullptr,
                       (const float*)nullptr, (const float*)nullptr);
    hipLaunchKernelGGL((gemm8<1>), dim3(256), dim3(512), 131072, stream,
                       W_bf, Zt, (void*)out, conv_b, S, out_b);
  } else {
    hipLaunchKernelGGL(prep_kernel, dim3(2048), dim3(256), 0, stream,
                       x, conv_w, out_w, x_bf, W_bf, weff, S);  // sections 0/1 only
    hipLaunchKernelGGL(gemmA_f32, dim3(64, NB), dim3(256), 0, stream, weff, x, Zt);
    hipLaunchKernelGGL(gemmB2, dim3(64, NB), dim3(256), 0, stream, W_bf, Zt, conv_b, S, out_b, out);
  }
}